// Round 7
// baseline (786.565 us; speedup 1.0000x reference)
//
#include <hip/hip_runtime.h>
#include <math.h>

// KWinners2d: x (128,256,32,32) f32, dutyCycle (1,256,1,1) f32
// k = round(0.1 * 256*32*32) = 26214 per batch row.
// 2 fused kernels, per-row "last-arriver" tails (no spin, dispatch-order safe):
//   histsel: per-block 2048-bin linear hist -> global slice; 16th arriver of a
//            row sums slices + finds bin b1 / residual rank r for that row.
//   masksel: write decided outputs (nt-stores); compact bin==b1 candidates;
//            16th arriver builds keys + 3-pass radix-select + fixup scatter.

#define NB 128
#define NC 256
#define ROW_N 262144            // 256*32*32
#define K_SEL 26214u
#define BINS 2048
#define BPR 16                  // blocks per row for streaming kernels
#define SLICE (ROW_N / BPR)     // 16384
#define NT 256
#define LCAP 1024               // per-block candidate cap (avg ~34)
#define CAND_CAP (BPR * LCAP)   // 16384 per row
#define LO_V (-8.0f)
#define SCALE_V 128.0f          // 2048 bins over [-8,8); |boosted| < 6.4 in-dist

typedef float nfloat4 __attribute__((ext_vector_type(4)));  // for nt-store

// Monotone linear bin; identical code in both kernels (explicit RN ops) so
// selection and compaction are bit-consistent. Clamp bins keep exactness even
// for out-of-range values (candidates in clamp bins resolve by exact radix).
__device__ __forceinline__ int vbin(float bv) {
    float f = __fmul_rn(__fsub_rn(bv, LO_V), SCALE_V);
    int b = (int)f;
    return min(max(b, 0), BINS - 1);
}
__device__ __forceinline__ unsigned int f2key(float f) {
    unsigned int u = __float_as_uint(f);
    return (u & 0x80000000u) ? ~u : (u | 0x80000000u);
}
__device__ __forceinline__ float key2f(unsigned int k) {
    unsigned int u = (k & 0x80000000u) ? (k ^ 0x80000000u) : ~k;
    return __uint_as_float(u);
}
// boost = exp(td - duty): fp32 subtract (matches JAX), exp in double ->
// correctly-rounded fp32; deterministic => bit-identical across kernels
// (absmax==0 in rounds 0-5 with this formula).
__device__ __forceinline__ float boost_of(float d) {
    const float td = 26214.0f / 262144.0f;   // exact in fp32
    float diff = td - d;
    return (float)exp((double)diff);
}

// Kernel 1: per-block hist slice; last arriver of each row does select1 tail.
__global__ void __launch_bounds__(NT) histsel_kernel(const float* __restrict__ x,
        const float* __restrict__ duty, unsigned int* __restrict__ hist,
        unsigned int* __restrict__ done,
        unsigned int* __restrict__ bin_out, unsigned int* __restrict__ k_out) {
    __shared__ unsigned int h[BINS];
    __shared__ unsigned int suf[NT];
    __shared__ float bl[16];
    __shared__ int lastf;
    const int row = blockIdx.x >> 4;
    const int j = blockIdx.x & 15;
    const int t = threadIdx.x;
    for (int i = t; i < BINS; i += NT) h[i] = 0u;
    if (t < 16) bl[t] = boost_of(duty[j * 16 + t]);
    __syncthreads();
    const float4* __restrict__ xp =
        (const float4*)(x + (size_t)row * ROW_N + (size_t)j * SLICE);
#pragma unroll
    for (int i = 0; i < SLICE / (4 * NT); ++i) {
        const int idx4 = t + i * NT;
        float4 v = xp[idx4];
        const float b = bl[(idx4 * 4) >> 10];   // 4 consecutive elems share channel
        atomicAdd(&h[vbin(__fmul_rn(v.x, b))], 1u);
        atomicAdd(&h[vbin(__fmul_rn(v.y, b))], 1u);
        atomicAdd(&h[vbin(__fmul_rn(v.z, b))], 1u);
        atomicAdd(&h[vbin(__fmul_rn(v.w, b))], 1u);
    }
    __syncthreads();
    unsigned int* __restrict__ gh = hist + (size_t)blockIdx.x * BINS;
    for (int i = t; i < BINS; i += NT) gh[i] = h[i];
    __threadfence();                         // release slice
    if (t == 0) lastf = (atomicAdd(&done[row], 1u) == BPR - 1);
    __syncthreads();
    if (!lastf) return;
    __threadfence();                         // acquire other slices
    // ---- tail: select1 for this row (reuse h as the row histogram) ----
    const unsigned int* __restrict__ grh = hist + (size_t)row * BPR * BINS;
    for (int bin = t; bin < BINS; bin += NT) {
        unsigned int s = 0;
#pragma unroll
        for (int jj = 0; jj < BPR; ++jj) s += grh[jj * BINS + bin];
        h[bin] = s;
    }
    __syncthreads();
    constexpr int PER = BINS / NT;
    unsigned int loc[PER];
    unsigned int s = 0;
#pragma unroll
    for (int i = 0; i < PER; ++i) { loc[i] = h[t * PER + i]; s += loc[i]; }
    suf[t] = s;
    __syncthreads();
    for (int off = 1; off < NT; off <<= 1) {
        unsigned int v = (t + off < NT) ? suf[t + off] : 0u;
        __syncthreads();
        suf[t] += v;
        __syncthreads();
    }
    unsigned int cum = (t + 1 < NT) ? suf[t + 1] : 0u;   // strictly-above count
#pragma unroll
    for (int i = PER - 1; i >= 0; --i) {
        if (K_SEL > cum && K_SEL <= cum + loc[i]) {
            bin_out[row] = (unsigned int)(t * PER + i);
            k_out[row] = K_SEL - cum;
        }
        cum += loc[i];
    }
}

// One radix pass: among keys with (key & pmask)==pval, histogram
// (key>>shift)&(NBINS-1), find bin containing (descending) rank res[1];
// writes res[0]=bin, res[1]=residual rank. All threads participate.
template <int NBINS>
__device__ void radix_pass(const unsigned int* __restrict__ keys, unsigned int c,
        unsigned int pmask, unsigned int pval, int shift,
        unsigned int* h, unsigned int* suf, unsigned int* res) {
    const int t = threadIdx.x;
    const unsigned int r = res[1];          // set before entry (sync'd)
    for (int i = t; i < NBINS; i += NT) h[i] = 0u;
    __syncthreads();
    for (unsigned int i = t; i < c; i += NT) {
        unsigned int k = keys[i];
        if ((k & pmask) == pval)
            atomicAdd(&h[(k >> shift) & (unsigned int)(NBINS - 1)], 1u);
    }
    __syncthreads();
    constexpr int PER = NBINS / NT;
    unsigned int loc[PER];
    unsigned int s = 0;
#pragma unroll
    for (int i = 0; i < PER; ++i) { loc[i] = h[t * PER + i]; s += loc[i]; }
    suf[t] = s;
    __syncthreads();
    for (int off = 1; off < NT; off <<= 1) {
        unsigned int v = (t + off < NT) ? suf[t + off] : 0u;
        __syncthreads();
        suf[t] += v;
        __syncthreads();
    }
    unsigned int cum = (t + 1 < NT) ? suf[t + 1] : 0u;
#pragma unroll
    for (int i = PER - 1; i >= 0; --i) {
        if (r > cum && r <= cum + loc[i]) {
            res[0] = (unsigned int)(t * PER + i);
            res[1] = r - cum;
        }
        cum += loc[i];
    }
    __syncthreads();
}

// Kernel 2: streaming mask + compaction; last arriver of each row does the
// exact radix-select over that row's candidates + fixup scatter.
__global__ void __launch_bounds__(NT) masksel_kernel(const float* __restrict__ x,
        const float* __restrict__ duty, const unsigned int* __restrict__ bin1,
        const unsigned int* __restrict__ k1, unsigned int* __restrict__ ccnt,
        uint2* __restrict__ cand, unsigned int* __restrict__ keyscratch,
        unsigned int* __restrict__ done, float* __restrict__ out) {
    __shared__ float bl[16];
    __shared__ unsigned int lidx[LCAP];
    __shared__ float lval[LCAP];
    __shared__ unsigned int lcnt;
    __shared__ int lastf;
    __shared__ float bl256[NC];
    __shared__ unsigned int rh[BINS];
    __shared__ unsigned int suf[NT];
    __shared__ unsigned int res[2];
    __shared__ unsigned int cb[BPR + 1];
    const int row = blockIdx.x >> 4;
    const int j = blockIdx.x & 15;
    const int t = threadIdx.x;
    if (t == 0) lcnt = 0u;
    if (t < 16) bl[t] = boost_of(duty[j * 16 + t]);
    __syncthreads();
    const int b1 = (int)bin1[row];
    const size_t base = (size_t)row * ROW_N + (size_t)j * SLICE;
    const float4* __restrict__ xp = (const float4*)(x + base);
    nfloat4* __restrict__ op = (nfloat4*)(out + base);
#pragma unroll
    for (int i = 0; i < SLICE / (4 * NT); ++i) {
        const int idx4 = t + i * NT;
        float4 v = xp[idx4];
        const float b = bl[(idx4 * 4) >> 10];
        const unsigned int e0 = (unsigned int)(idx4 * 4);
        nfloat4 o;
        {
            int bb = vbin(__fmul_rn(v.x, b));
            o.x = (bb > b1) ? v.x : 0.0f;
            if (bb == b1) { unsigned int p = atomicAdd(&lcnt, 1u);
                            if (p < LCAP) { lidx[p] = e0 + 0u; lval[p] = v.x; } }
        }
        {
            int bb = vbin(__fmul_rn(v.y, b));
            o.y = (bb > b1) ? v.y : 0.0f;
            if (bb == b1) { unsigned int p = atomicAdd(&lcnt, 1u);
                            if (p < LCAP) { lidx[p] = e0 + 1u; lval[p] = v.y; } }
        }
        {
            int bb = vbin(__fmul_rn(v.z, b));
            o.z = (bb > b1) ? v.z : 0.0f;
            if (bb == b1) { unsigned int p = atomicAdd(&lcnt, 1u);
                            if (p < LCAP) { lidx[p] = e0 + 2u; lval[p] = v.z; } }
        }
        {
            int bb = vbin(__fmul_rn(v.w, b));
            o.w = (bb > b1) ? v.w : 0.0f;
            if (bb == b1) { unsigned int p = atomicAdd(&lcnt, 1u);
                            if (p < LCAP) { lidx[p] = e0 + 3u; lval[p] = v.w; } }
        }
        __builtin_nontemporal_store(o, &op[idx4]);
    }
    __syncthreads();
    const unsigned int m = min(lcnt, (unsigned int)LCAP);
    if (t == 0) ccnt[blockIdx.x] = m;
    uint2* __restrict__ crw = cand + (size_t)row * CAND_CAP + (size_t)j * LCAP;
    const unsigned int joff = (unsigned int)(j * SLICE);
    for (unsigned int i = t; i < m; i += NT)
        crw[i] = make_uint2(lidx[i] + joff, __float_as_uint(lval[i]));
    __threadfence();                         // release candidates + count
    if (t == 0) lastf = (atomicAdd(&done[row], 1u) == BPR - 1);
    __syncthreads();
    if (!lastf) return;
    __threadfence();                         // acquire other blocks' candidates
    // ---- tail: exact r-th largest among this row's candidates + fixup ----
    bl256[t] = boost_of(duty[t]);            // NT == NC
    if (t == 0) {
        unsigned int acc = 0;
        for (int jj = 0; jj < BPR; ++jj) { cb[jj] = acc; acc += ccnt[row * BPR + jj]; }
        cb[BPR] = acc;
        res[1] = k1[row];
    }
    __syncthreads();
    const unsigned int c = cb[BPR];
    const uint2* __restrict__ cr = cand + (size_t)row * CAND_CAP;
    unsigned int* __restrict__ ks = keyscratch + (size_t)row * CAND_CAP;
    for (int jj = 0; jj < BPR; ++jj) {
        const unsigned int cj = cb[jj + 1] - cb[jj];
        const unsigned int b0 = cb[jj];
        for (unsigned int i = t; i < cj; i += NT) {
            uint2 e = cr[jj * LCAP + i];
            float bv = __fmul_rn(__uint_as_float(e.y), bl256[e.x >> 10]);
            ks[b0 + i] = f2key(bv);
        }
    }
    __syncthreads();
    radix_pass<2048>(ks, c, 0u, 0u, 21, rh, suf, res);
    const unsigned int r1 = res[0];
    radix_pass<2048>(ks, c, 0xFFE00000u, r1 << 21, 10, rh, suf, res);
    const unsigned int r2 = res[0];
    radix_pass<1024>(ks, c, 0xFFFFFC00u, (r1 << 21) | (r2 << 10), 0, rh, suf, res);
    const unsigned int r3 = res[0];
    const float tf = key2f((r1 << 21) | (r2 << 10) | r3);
    float* __restrict__ orow = out + (size_t)row * ROW_N;
    for (int jj = 0; jj < BPR; ++jj) {
        const unsigned int cj = cb[jj + 1] - cb[jj];
        for (unsigned int i = t; i < cj; i += NT) {
            uint2 e = cr[jj * LCAP + i];
            float val = __uint_as_float(e.y);
            float bv = __fmul_rn(val, bl256[e.x >> 10]);
            if (bv >= tf) orow[e.x] = val;
        }
    }
}

extern "C" void kernel_launch(void* const* d_in, const int* in_sizes, int n_in,
                              void* d_out, int out_size, void* d_ws, size_t ws_size,
                              hipStream_t stream) {
    const float* x = (const float*)d_in[0];
    const float* duty = (const float*)d_in[1];
    float* out = (float*)d_out;
    char* ws = (char*)d_ws;

    unsigned int* bin1  = (unsigned int*)(ws);             // 512 B
    unsigned int* k1    = (unsigned int*)(ws + 512);       // 512 B
    unsigned int* done1 = (unsigned int*)(ws + 1024);      // 512 B (needs zero)
    unsigned int* done2 = (unsigned int*)(ws + 1536);      // 512 B (needs zero)
    unsigned int* ccnt  = (unsigned int*)(ws + 4096);      // 8 KB
    unsigned int* keyscratch = (unsigned int*)(ws + 16384);                  // 8 MB
    unsigned int* hist  = (unsigned int*)(ws + 16384 + (size_t)NB * CAND_CAP * 4);  // 16 MB
    uint2* cand = (uint2*)((char*)hist + (size_t)NB * BPR * BINS * 4);       // 16 MB

    hipMemsetAsync(done1, 0, 1024, stream);   // zero done1 + done2

    histsel_kernel<<<NB * BPR, NT, 0, stream>>>(x, duty, hist, done1, bin1, k1);
    masksel_kernel<<<NB * BPR, NT, 0, stream>>>(x, duty, bin1, k1, ccnt, cand,
                                                keyscratch, done2, out);
}

// Round 8
// 296.854 us; speedup vs baseline: 2.6497x; 2.6497x over previous
//
#include <hip/hip_runtime.h>
#include <math.h>

// KWinners2d: x (128,256,32,32) f32, dutyCycle (1,256,1,1) f32
// k = round(0.1 * 256*32*32) = 26214 per batch row.
// 3 dispatches, NO fences (round-7 lesson: __threadfence = per-block L2
// writeback on non-coherent XCD L2s => 341us stall), NO memsets:
//   hist:    per-block private 2048-bin hist -> exclusive global slice
//   mask:    each block re-derives its row's threshold bin b1 from the 16
//            slices (regs+suffix-scan), streams mask output (nt-stores),
//            compacts bin==b1 candidates to an exclusive region
//   select2: re-derives (b1, r), exact 3-pass LDS radix-select + fixup

#define NB 128
#define NC 256
#define ROW_N 262144            // 256*32*32
#define K_SEL 26214u
#define BINS 2048
#define BPR 16                  // blocks per row for streaming kernels
#define SLICE (ROW_N / BPR)     // 16384
#define NT 256
#define PER 8                   // BINS/NT
#define LCAP 1024               // per-block candidate cap (avg ~34)
#define CAND_CAP (BPR * LCAP)   // 16384 per row
#define SCALE_V 128.0f          // 2048 bins over [-8,8)
#define BIAS_V 1024.0f          // -LO*SCALE

typedef float nfloat4 __attribute__((ext_vector_type(4)));  // for nt-store

// Monotone bin; IDENTICAL code in all kernels (correctly-rounded fma) so
// binning is bit-consistent. Clamp bins keep exactness for out-of-range
// values (they become candidates resolved by exact radix).
__device__ __forceinline__ int vbin(float bv) {
    float f = __fmaf_rn(bv, SCALE_V, BIAS_V);
    int b = (int)f;
    return min(max(b, 0), BINS - 1);
}
__device__ __forceinline__ unsigned int f2key(float f) {
    unsigned int u = __float_as_uint(f);
    return (u & 0x80000000u) ? ~u : (u | 0x80000000u);
}
__device__ __forceinline__ float key2f(unsigned int k) {
    unsigned int u = (k & 0x80000000u) ? (k ^ 0x80000000u) : ~k;
    return __uint_as_float(u);
}
// boost = exp(td - duty): fp32 subtract (matches JAX), exp in double ->
// correctly-rounded fp32; deterministic => bit-identical across kernels
// (absmax==0 in all passing rounds with this formula).
__device__ __forceinline__ float boost_of(float d) {
    const float td = 26214.0f / 262144.0f;   // exact in fp32
    float diff = td - d;
    return (float)exp((double)diff);
}

// Shared helper: sum this row's 16 hist slices for bins [t*8, t*8+8) into
// loc[], suffix-scan across threads, return strictly-above count at chunk
// start via *cum_out; caller scans loc[] descending for the target bin.
__device__ __forceinline__ void row_scan(const unsigned int* __restrict__ grh,
        unsigned int* loc, unsigned int* suf, unsigned int* cum_out) {
    const int t = threadIdx.x;
#pragma unroll
    for (int i = 0; i < PER; ++i) loc[i] = 0u;
#pragma unroll
    for (int jj = 0; jj < BPR; ++jj) {
        const uint4* p = (const uint4*)(grh + jj * BINS + t * PER);
        uint4 a = p[0], b = p[1];
        loc[0] += a.x; loc[1] += a.y; loc[2] += a.z; loc[3] += a.w;
        loc[4] += b.x; loc[5] += b.y; loc[6] += b.z; loc[7] += b.w;
    }
    unsigned int s = 0;
#pragma unroll
    for (int i = 0; i < PER; ++i) s += loc[i];
    suf[t] = s;
    __syncthreads();
    for (int off = 1; off < NT; off <<= 1) {
        unsigned int v = (t + off < NT) ? suf[t + off] : 0u;
        __syncthreads();
        suf[t] += v;
        __syncthreads();
    }
    *cum_out = (t + 1 < NT) ? suf[t + 1] : 0u;   // strictly-above this chunk
}

// Kernel 1: per-block 2048-bin histogram -> exclusive slice (no atomics).
__global__ void __launch_bounds__(NT) hist_kernel(const float* __restrict__ x,
        const float* __restrict__ duty, unsigned int* __restrict__ hist) {
    __shared__ unsigned int h[BINS];
    __shared__ float bl[16];
    const int row = blockIdx.x >> 4;
    const int j = blockIdx.x & 15;
    const int t = threadIdx.x;
    for (int i = t; i < BINS; i += NT) h[i] = 0u;
    if (t < 16) bl[t] = boost_of(duty[j * 16 + t]);
    __syncthreads();
    const float4* __restrict__ xp =
        (const float4*)(x + (size_t)row * ROW_N + (size_t)j * SLICE);
#pragma unroll
    for (int i = 0; i < SLICE / (4 * NT); ++i) {
        const int idx4 = t + i * NT;
        float4 v = xp[idx4];
        const float b = bl[(idx4 * 4) >> 10];   // 4 consecutive elems share channel
        atomicAdd(&h[vbin(__fmul_rn(v.x, b))], 1u);
        atomicAdd(&h[vbin(__fmul_rn(v.y, b))], 1u);
        atomicAdd(&h[vbin(__fmul_rn(v.z, b))], 1u);
        atomicAdd(&h[vbin(__fmul_rn(v.w, b))], 1u);
    }
    __syncthreads();
    unsigned int* __restrict__ gh = hist + (size_t)blockIdx.x * BINS;
    for (int i = t; i < BINS; i += NT) gh[i] = h[i];
}

// Kernel 2: derive b1 in-block, stream mask output, compact candidates.
__global__ void __launch_bounds__(NT) mask_kernel(const float* __restrict__ x,
        const float* __restrict__ duty, const unsigned int* __restrict__ hist,
        unsigned int* __restrict__ ccnt, uint2* __restrict__ cand,
        float* __restrict__ out) {
    __shared__ float bl[16];
    __shared__ unsigned int lidx[LCAP];
    __shared__ float lval[LCAP];
    __shared__ unsigned int lcnt;
    __shared__ unsigned int suf[NT];
    __shared__ unsigned int sb1;
    const int row = blockIdx.x >> 4;
    const int j = blockIdx.x & 15;
    const int t = threadIdx.x;
    if (t == 0) lcnt = 0u;
    if (t < 16) bl[t] = boost_of(duty[j * 16 + t]);
    // ---- derive b1 for this row (redundant per block; kills select1 launch) ----
    unsigned int loc[PER], cum;
    row_scan(hist + (size_t)row * BPR * BINS, loc, suf, &cum);
#pragma unroll
    for (int i = PER - 1; i >= 0; --i) {
        if (K_SEL > cum && K_SEL <= cum + loc[i]) sb1 = (unsigned int)(t * PER + i);
        cum += loc[i];
    }
    __syncthreads();
    const int b1 = (int)sb1;
    // ---- stream mask + compact ----
    const size_t base = (size_t)row * ROW_N + (size_t)j * SLICE;
    const float4* __restrict__ xp = (const float4*)(x + base);
    nfloat4* __restrict__ op = (nfloat4*)(out + base);
#pragma unroll
    for (int i = 0; i < SLICE / (4 * NT); ++i) {
        const int idx4 = t + i * NT;
        float4 v = xp[idx4];
        const float b = bl[(idx4 * 4) >> 10];
        const unsigned int e0 = (unsigned int)(idx4 * 4);
        nfloat4 o;
        {
            int bb = vbin(__fmul_rn(v.x, b));
            o.x = (bb > b1) ? v.x : 0.0f;
            if (bb == b1) { unsigned int p = atomicAdd(&lcnt, 1u);
                            if (p < LCAP) { lidx[p] = e0 + 0u; lval[p] = v.x; } }
        }
        {
            int bb = vbin(__fmul_rn(v.y, b));
            o.y = (bb > b1) ? v.y : 0.0f;
            if (bb == b1) { unsigned int p = atomicAdd(&lcnt, 1u);
                            if (p < LCAP) { lidx[p] = e0 + 1u; lval[p] = v.y; } }
        }
        {
            int bb = vbin(__fmul_rn(v.z, b));
            o.z = (bb > b1) ? v.z : 0.0f;
            if (bb == b1) { unsigned int p = atomicAdd(&lcnt, 1u);
                            if (p < LCAP) { lidx[p] = e0 + 2u; lval[p] = v.z; } }
        }
        {
            int bb = vbin(__fmul_rn(v.w, b));
            o.w = (bb > b1) ? v.w : 0.0f;
            if (bb == b1) { unsigned int p = atomicAdd(&lcnt, 1u);
                            if (p < LCAP) { lidx[p] = e0 + 3u; lval[p] = v.w; } }
        }
        __builtin_nontemporal_store(o, &op[idx4]);
    }
    __syncthreads();
    const unsigned int m = min(lcnt, (unsigned int)LCAP);
    if (t == 0) ccnt[blockIdx.x] = m;
    uint2* __restrict__ crw = cand + (size_t)row * CAND_CAP + (size_t)j * LCAP;
    const unsigned int joff = (unsigned int)(j * SLICE);
    for (unsigned int i = t; i < m; i += NT)
        crw[i] = make_uint2(lidx[i] + joff, __float_as_uint(lval[i]));
}

// One radix pass over LDS keys (see round-5 notes); res[0]=bin, res[1]=rank.
template <int NBINS>
__device__ void radix_pass(const unsigned int* __restrict__ keys, unsigned int c,
        unsigned int pmask, unsigned int pval, int shift,
        unsigned int* h, unsigned int* suf, unsigned int* res) {
    const int t = threadIdx.x;
    const unsigned int r = res[1];
    for (int i = t; i < NBINS; i += NT) h[i] = 0u;
    __syncthreads();
    for (unsigned int i = t; i < c; i += NT) {
        unsigned int k = keys[i];
        if ((k & pmask) == pval)
            atomicAdd(&h[(k >> shift) & (unsigned int)(NBINS - 1)], 1u);
    }
    __syncthreads();
    constexpr int P2 = NBINS / NT;
    unsigned int loc[P2];
    unsigned int s = 0;
#pragma unroll
    for (int i = 0; i < P2; ++i) { loc[i] = h[t * P2 + i]; s += loc[i]; }
    suf[t] = s;
    __syncthreads();
    for (int off = 1; off < NT; off <<= 1) {
        unsigned int v = (t + off < NT) ? suf[t + off] : 0u;
        __syncthreads();
        suf[t] += v;
        __syncthreads();
    }
    unsigned int cum = (t + 1 < NT) ? suf[t + 1] : 0u;
#pragma unroll
    for (int i = P2 - 1; i >= 0; --i) {
        if (r > cum && r <= cum + loc[i]) {
            res[0] = (unsigned int)(t * P2 + i);
            res[1] = r - cum;
        }
        cum += loc[i];
    }
    __syncthreads();
}

// Kernel 3: re-derive (b1, r); exact radix-select among candidates + fixup.
__global__ void __launch_bounds__(NT) select2_kernel(const float* __restrict__ duty,
        const unsigned int* __restrict__ hist, const unsigned int* __restrict__ ccnt,
        const uint2* __restrict__ cand, float* __restrict__ out) {
    __shared__ unsigned int keys[CAND_CAP];   // 64 KB
    __shared__ unsigned int rh[BINS];         // 8 KB
    __shared__ unsigned int suf[NT];
    __shared__ unsigned int res[2];
    __shared__ float bl256[NC];
    __shared__ unsigned int cb[BPR + 1];
    const int row = blockIdx.x;
    const int t = threadIdx.x;
    bl256[t] = boost_of(duty[t]);             // NT == NC
    // ---- derive (b1, r) ----
    unsigned int loc[PER], cum;
    row_scan(hist + (size_t)row * BPR * BINS, loc, suf, &cum);
#pragma unroll
    for (int i = PER - 1; i >= 0; --i) {
        if (K_SEL > cum && K_SEL <= cum + loc[i]) res[1] = K_SEL - cum;
        cum += loc[i];
    }
    if (t == 0) {
        unsigned int acc = 0;
        for (int jj = 0; jj < BPR; ++jj) { cb[jj] = acc; acc += ccnt[row * BPR + jj]; }
        cb[BPR] = acc;
    }
    __syncthreads();
    const unsigned int c = cb[BPR];
    const uint2* __restrict__ cr = cand + (size_t)row * CAND_CAP;
    for (int jj = 0; jj < BPR; ++jj) {
        const unsigned int cj = cb[jj + 1] - cb[jj];
        const unsigned int b0 = cb[jj];
        for (unsigned int i = t; i < cj; i += NT) {
            uint2 e = cr[jj * LCAP + i];
            float bv = __fmul_rn(__uint_as_float(e.y), bl256[e.x >> 10]);
            keys[b0 + i] = f2key(bv);
        }
    }
    __syncthreads();
    radix_pass<2048>(keys, c, 0u, 0u, 21, rh, suf, res);
    const unsigned int r1 = res[0];
    radix_pass<2048>(keys, c, 0xFFE00000u, r1 << 21, 10, rh, suf, res);
    const unsigned int r2 = res[0];
    radix_pass<1024>(keys, c, 0xFFFFFC00u, (r1 << 21) | (r2 << 10), 0, rh, suf, res);
    const unsigned int r3 = res[0];
    const float tf = key2f((r1 << 21) | (r2 << 10) | r3);
    float* __restrict__ orow = out + (size_t)row * ROW_N;
    for (int jj = 0; jj < BPR; ++jj) {
        const unsigned int cj = cb[jj + 1] - cb[jj];
        for (unsigned int i = t; i < cj; i += NT) {
            uint2 e = cr[jj * LCAP + i];
            float val = __uint_as_float(e.y);
            float bv = __fmul_rn(val, bl256[e.x >> 10]);
            if (bv >= tf) orow[e.x] = val;
        }
    }
}

extern "C" void kernel_launch(void* const* d_in, const int* in_sizes, int n_in,
                              void* d_out, int out_size, void* d_ws, size_t ws_size,
                              hipStream_t stream) {
    const float* x = (const float*)d_in[0];
    const float* duty = (const float*)d_in[1];
    float* out = (float*)d_out;
    char* ws = (char*)d_ws;

    unsigned int* ccnt = (unsigned int*)ws;                  // 8 KB (exclusive writes)
    unsigned int* hist = (unsigned int*)(ws + 16384);        // 16 MB (exclusive slices)
    uint2* cand = (uint2*)(ws + 16384 + (size_t)NB * BPR * BINS * 4);  // 16 MB

    hist_kernel<<<NB * BPR, NT, 0, stream>>>(x, duty, hist);
    mask_kernel<<<NB * BPR, NT, 0, stream>>>(x, duty, hist, ccnt, cand, out);
    select2_kernel<<<NB, NT, 0, stream>>>(duty, hist, ccnt, cand, out);
}